// Round 9
// baseline (416.871 us; speedup 1.0000x reference)
//
#include <hip/hip_runtime.h>
#include <math.h>

#define IOTA_F (1.0f / 137.0f)
#define PHI_F  0.618033988749894f
#define NBLK   512

__device__ __forceinline__ float sigm(float x) { return 1.0f / (1.0f + expf(-x)); }

__device__ __forceinline__ float nan2num(float v) {
    if (isnan(v)) return IOTA_F;
    if (isinf(v)) return v > 0.0f ? 1.0f : IOTA_F;
    return v;
}

// ---------------------------------------------------------------------------
// Software grid barrier (all NBLK blocks co-resident by construction).
// flags[NBLK] + go at flags[NBLK]; zeroed by hipMemsetAsync each call.
// Generations g = 1,2,3 within a call (monotone, so stale never passes).
// Device-scope (AGENT) atomics are coherent across XCD L2s.
// ---------------------------------------------------------------------------
__device__ __forceinline__ void grid_barrier(int* flags, int g) {
    __syncthreads();
    __threadfence();                               // release all prior writes
    const int bid = blockIdx.x, tid = threadIdx.x;
    int* go = flags + NBLK;
    if (bid == 0) {
        if (tid == 0)
            __hip_atomic_store(&flags[0], g, __ATOMIC_RELEASE, __HIP_MEMORY_SCOPE_AGENT);
        for (int i = tid; i < NBLK; i += 256) {
            int cnt = 0;
            while (__hip_atomic_load(&flags[i], __ATOMIC_ACQUIRE, __HIP_MEMORY_SCOPE_AGENT) < g) {
                __builtin_amdgcn_s_sleep(1);
                if (++cnt > (1 << 24)) break;      // fail loudly, don't wedge
            }
        }
        __syncthreads();
        __threadfence();
        if (tid == 0)
            __hip_atomic_store(go, g, __ATOMIC_RELEASE, __HIP_MEMORY_SCOPE_AGENT);
    } else {
        if (tid == 0) {
            __hip_atomic_store(&flags[bid], g, __ATOMIC_RELEASE, __HIP_MEMORY_SCOPE_AGENT);
            int cnt = 0;
            while (__hip_atomic_load(go, __ATOMIC_ACQUIRE, __HIP_MEMORY_SCOPE_AGENT) < g) {
                __builtin_amdgcn_s_sleep(1);
                if (++cnt > (1 << 24)) break;
            }
        }
        __syncthreads();
        __threadfence();                           // acquire for whole block
    }
}

// ---------------------------------------------------------------------------
// Phase 0: every block computes the full pre-stage into its own LDS B.
// instance_norm(5) -> rfft(5) -> re*im -> sigmoid -> softmax(3) -> bilinear
// -> mask(u1). Inputs (40+72 KB) are L2-resident after first touch.
// ---------------------------------------------------------------------------
__device__ void pre_into_lds(int tid,
                             const float* __restrict__ signal,
                             const float* __restrict__ u1,
                             const float* __restrict__ bilW,
                             const float* __restrict__ bilb,
                             float* __restrict__ Bsf)   // [9][2048] in LDS
{
    #pragma unroll
    for (int k = 0; k < 8; ++k) {
        const int s = k * 256 + tid;

        float x0 = signal[0 * 2048 + s];
        float x1 = signal[1 * 2048 + s];
        float x2 = signal[2 * 2048 + s];
        float x3 = signal[3 * 2048 + s];
        float x4 = signal[4 * 2048 + s];

        float mean = (x0 + x1 + x2 + x3 + x4) * 0.2f;
        float d0 = x0 - mean, d1 = x1 - mean, d2 = x2 - mean, d3 = x3 - mean, d4 = x4 - mean;
        float var = (d0 * d0 + d1 * d1 + d2 * d2 + d3 * d3 + d4 * d4) * 0.2f;
        float r = 1.0f / sqrtf(var + 1e-9f);
        d0 *= r; d1 *= r; d2 *= r; d3 *= r; d4 *= r;

        const float c1 = 0.30901699437494742f;   // cos(2pi/5)
        const float c2 = -0.80901699437494745f;  // cos(4pi/5)
        const float s1 = 0.95105651629515357f;   // sin(2pi/5)
        const float s2 = 0.58778525229247314f;   // sin(4pi/5)

        float re1 = d0 + c1 * (d1 + d4) + c2 * (d2 + d3);
        float im1 = -(s1 * (d1 - d4) + s2 * (d2 - d3));
        float re2 = d0 + c2 * (d1 + d4) + c1 * (d2 + d3);
        float im2 = -s2 * (d1 - d4) + s1 * (d2 - d3);

        float p1 = nan2num(re1 * im1);
        float p2 = nan2num(re2 * im2);
        float g0 = 0.5f;                 // k=0: imag == 0 -> sigmoid(0) = 0.5
        float g1 = sigm(p1);
        float g2 = sigm(p2);

        float mx = fmaxf(g0, fmaxf(g1, g2));
        float e0 = expf(g0 - mx), e1 = expf(g1 - mx), e2 = expf(g2 - mx);
        float inv = 1.0f / (e0 + e1 + e2);
        float w[3] = { e0 * inv, e1 * inv, e2 * inv };

        #pragma unroll
        for (int kk = 0; kk < 9; ++kk) {
            float acc = bilb[kk];
            #pragma unroll
            for (int i = 0; i < 3; ++i)
                #pragma unroll
                for (int j = 0; j < 3; ++j)
                    acc += w[i] * bilW[kk * 9 + i * 3 + j] * w[j];
            float mask = (u1[kk * 2048 + s] < PHI_F) ? 1.0f : 0.0f;
            Bsf[kk * 2048 + s] = IOTA_F + acc * mask;
        }
    }
}

// ---------------------------------------------------------------------------
// stage B[9][2048] global -> LDS (18 float4 per thread, coalesced)
// ---------------------------------------------------------------------------
__device__ __forceinline__ void stage_B(int tid, const float* __restrict__ Bv,
                                        float4* __restrict__ Bs4)
{
    const float4* __restrict__ Bg = reinterpret_cast<const float4*>(Bv);
    #pragma unroll
    for (int k = 0; k < 18; ++k)
        Bs4[tid + k * 256] = Bg[tid + k * 256];
}

// ---------------------------------------------------------------------------
// LSTM phase (round-4 proven loop, B from LDS). Block covers 4 q-columns;
// wave w = K-chunk of 512; group g owns q = bid*4+g and rows {q,4096+q,6144+q}
// (f-gate dead: c0 = 0). Epilogue: h = sig(o)*tanh(sig(i)*tanh(g)) (+mask).
// ---------------------------------------------------------------------------
template <bool MASK>
__device__ void lstm_phase(int bid, int tid,
                           const float4* __restrict__ Bs4,
                           float* __restrict__ redf,      // [4][4][3][9]
                           const float* __restrict__ W,   // [8192][2048]
                           const float* __restrict__ b1,
                           const float* __restrict__ b2,
                           const float* __restrict__ u,
                           float* __restrict__ Bout)      // [9][2048]
{
    const int w    = tid >> 6;
    const int lane = tid & 63;
    const int grp  = lane >> 4;
    const int li   = lane & 15;

    const int q = bid * 4 + grp;

    const float4* __restrict__ Wi = reinterpret_cast<const float4*>(W) + (size_t)q * 512;
    const float4* __restrict__ Wg = Wi + (size_t)4096 * 512;
    const float4* __restrict__ Wo = Wi + (size_t)6144 * 512;

    float acc[3][9];
    #pragma unroll
    for (int r = 0; r < 3; ++r)
        #pragma unroll
        for (int m = 0; m < 9; ++m) acc[r][m] = 0.0f;

    const int kb4 = w * 128;

    #pragma unroll 2
    for (int it = 0; it < 8; ++it) {
        const int idx = kb4 + it * 16 + li;
        float4 wv0 = Wi[idx];
        float4 wv1 = Wg[idx];
        float4 wv2 = Wo[idx];
        #pragma unroll
        for (int m = 0; m < 9; ++m) {
            float4 bv = Bs4[m * 512 + idx];
            acc[0][m] = fmaf(wv0.x, bv.x, acc[0][m]);
            acc[0][m] = fmaf(wv0.y, bv.y, acc[0][m]);
            acc[0][m] = fmaf(wv0.z, bv.z, acc[0][m]);
            acc[0][m] = fmaf(wv0.w, bv.w, acc[0][m]);
            acc[1][m] = fmaf(wv1.x, bv.x, acc[1][m]);
            acc[1][m] = fmaf(wv1.y, bv.y, acc[1][m]);
            acc[1][m] = fmaf(wv1.z, bv.z, acc[1][m]);
            acc[1][m] = fmaf(wv1.w, bv.w, acc[1][m]);
            acc[2][m] = fmaf(wv2.x, bv.x, acc[2][m]);
            acc[2][m] = fmaf(wv2.y, bv.y, acc[2][m]);
            acc[2][m] = fmaf(wv2.z, bv.z, acc[2][m]);
            acc[2][m] = fmaf(wv2.w, bv.w, acc[2][m]);
        }
    }

    #pragma unroll
    for (int r = 0; r < 3; ++r)
        #pragma unroll
        for (int m = 0; m < 9; ++m) {
            float v = acc[r][m];
            v += __shfl_xor(v, 1);
            v += __shfl_xor(v, 2);
            v += __shfl_xor(v, 4);
            v += __shfl_xor(v, 8);
            acc[r][m] = v;
        }

    if (li == 0) {
        #pragma unroll
        for (int r = 0; r < 3; ++r)
            #pragma unroll
            for (int m = 0; m < 9; ++m)
                redf[((w * 4 + grp) * 3 + r) * 9 + m] = acc[r][m];
    }
    __syncthreads();

    if (tid < 36) {
        const int qq = tid / 9;
        const int m  = tid - qq * 9;
        const int qg = bid * 4 + qq;
        float iv = 0.0f, gv = 0.0f, ov = 0.0f;
        #pragma unroll
        for (int ww = 0; ww < 4; ++ww) {
            iv += redf[((ww * 4 + qq) * 3 + 0) * 9 + m];
            gv += redf[((ww * 4 + qq) * 3 + 1) * 9 + m];
            ov += redf[((ww * 4 + qq) * 3 + 2) * 9 + m];
        }
        iv += b1[qg] + b2[qg];
        gv += b1[4096 + qg] + b2[4096 + qg];
        ov += b1[6144 + qg] + b2[6144 + qg];
        float c = sigm(iv) * tanhf(gv);
        float h = sigm(ov) * tanhf(c);
        if (MASK) h = IOTA_F + h * ((u[m * 2048 + qg] < PHI_F) ? 1.0f : 0.0f);
        Bout[m * 2048 + qg] = h;
    }
}

// ---------------------------------------------------------------------------
// Linear phase (round-4 proven loop, B from LDS). Block covers 20 rows.
// ---------------------------------------------------------------------------
__device__ void linear_phase(int bid, int tid,
                             const float4* __restrict__ Bs4,
                             float* __restrict__ redf,       // [4][20][9]
                             const float* __restrict__ W,    // [10240][2048]
                             const float* __restrict__ bias,
                             float* __restrict__ Out)        // [9][10240]
{
    constexpr int R = 5;
    const int w    = tid >> 6;
    const int lane = tid & 63;
    const int grp  = lane >> 4;
    const int li   = lane & 15;

    const int rowB = bid * 4 * R;
    const int row0 = rowB + grp * R;

    const float4* __restrict__ W0 = reinterpret_cast<const float4*>(W) + (size_t)row0 * 512;

    float acc[R][9];
    #pragma unroll
    for (int r = 0; r < R; ++r)
        #pragma unroll
        for (int m = 0; m < 9; ++m) acc[r][m] = 0.0f;

    const int kb4 = w * 128;

    #pragma unroll 2
    for (int it = 0; it < 8; ++it) {
        const int idx = kb4 + it * 16 + li;
        float4 wv[R];
        #pragma unroll
        for (int r = 0; r < R; ++r) wv[r] = W0[(size_t)r * 512 + idx];
        #pragma unroll
        for (int m = 0; m < 9; ++m) {
            float4 bv = Bs4[m * 512 + idx];
            #pragma unroll
            for (int r = 0; r < R; ++r) {
                acc[r][m] = fmaf(wv[r].x, bv.x, acc[r][m]);
                acc[r][m] = fmaf(wv[r].y, bv.y, acc[r][m]);
                acc[r][m] = fmaf(wv[r].z, bv.z, acc[r][m]);
                acc[r][m] = fmaf(wv[r].w, bv.w, acc[r][m]);
            }
        }
    }

    #pragma unroll
    for (int r = 0; r < R; ++r)
        #pragma unroll
        for (int m = 0; m < 9; ++m) {
            float v = acc[r][m];
            v += __shfl_xor(v, 1);
            v += __shfl_xor(v, 2);
            v += __shfl_xor(v, 4);
            v += __shfl_xor(v, 8);
            acc[r][m] = v;
        }

    if (li == 0) {
        #pragma unroll
        for (int r = 0; r < R; ++r)
            #pragma unroll
            for (int m = 0; m < 9; ++m)
                redf[(w * 4 * R + grp * R + r) * 9 + m] = acc[r][m];
    }
    __syncthreads();

    for (int t = tid; t < 4 * R * 9; t += 256) {
        const int row = t / 9;
        const int m   = t - row * 9;
        float v = redf[(0 * 4 * R + row) * 9 + m] + redf[(1 * 4 * R + row) * 9 + m]
                + redf[(2 * 4 * R + row) * 9 + m] + redf[(3 * 4 * R + row) * 9 + m];
        const int grow = rowB + row;
        Out[(size_t)m * 10240 + grow] = v + bias[grow];
    }
}

// ---------------------------------------------------------------------------
// Final phase (256 threads): t[s] = sum_k Z[a*18432+s*9+k]; instance-norm
// + softmax over 2048. t lives in the reused LDS B arena.
// ---------------------------------------------------------------------------
__device__ __forceinline__ float block_reduce256(float v, float* red, int tid, int op) {
    #pragma unroll
    for (int off = 32; off > 0; off >>= 1) {
        float o = __shfl_xor(v, off);
        v = op ? fmaxf(v, o) : (v + o);
    }
    __syncthreads();
    if ((tid & 63) == 0) red[tid >> 6] = v;
    __syncthreads();
    float r = op ? fmaxf(fmaxf(red[0], red[1]), fmaxf(red[2], red[3]))
                 : (red[0] + red[1] + red[2] + red[3]);
    return r;
}

__device__ void final_phase(int a, int tid, float* __restrict__ t, float* __restrict__ red,
                            const float* __restrict__ Z, float* __restrict__ out)
{
    for (int s = tid; s < 2048; s += 256) {
        const float* zp = Z + a * 18432 + s * 9;
        float acc = 0.0f;
        #pragma unroll
        for (int k = 0; k < 9; ++k) acc += zp[k];
        t[s] = acc;
    }
    __syncthreads();

    float l[8];
    #pragma unroll
    for (int j = 0; j < 8; ++j) l[j] = t[tid + j * 256];

    float lsum = 0.0f;
    #pragma unroll
    for (int j = 0; j < 8; ++j) lsum += l[j];
    float ssum = block_reduce256(lsum, red, tid, 0);
    float mean = ssum * (1.0f / 2048.0f);

    float vs = 0.0f;
    #pragma unroll
    for (int j = 0; j < 8; ++j) { l[j] -= mean; vs += l[j] * l[j]; }
    float vsum = block_reduce256(vs, red, tid, 0);
    float rstd = 1.0f / sqrtf(vsum * (1.0f / 2048.0f) + 1e-9f);

    float lmx = -1e30f;
    #pragma unroll
    for (int j = 0; j < 8; ++j) { l[j] *= rstd; lmx = fmaxf(lmx, l[j]); }
    float mx = block_reduce256(lmx, red, tid, 1);

    float es = 0.0f;
    #pragma unroll
    for (int j = 0; j < 8; ++j) { l[j] = expf(l[j] - mx); es += l[j]; }
    float esum = block_reduce256(es, red, tid, 0);
    float inv = 1.0f / esum;

    #pragma unroll
    for (int j = 0; j < 8; ++j)
        out[a * 2048 + tid + j * 256] = l[j] * inv;
}

// ---------------------------------------------------------------------------
// Persistent mega-kernel. Grid 512 x 256 = exactly 2 blocks/CU (LDS 76.6 KB
// -> 2/CU; VGPR capped by launch_bounds). 3 software grid barriers.
// ---------------------------------------------------------------------------
__global__ __launch_bounds__(256, 2) void k_mega(
    const float* __restrict__ signal, const float* __restrict__ u1,
    const float* __restrict__ u2, const float* __restrict__ bilW,
    const float* __restrict__ bilb,
    const float* __restrict__ Wih1, const float* __restrict__ bih1,
    const float* __restrict__ bhh1,
    const float* __restrict__ Wih2, const float* __restrict__ bih2,
    const float* __restrict__ bhh2,
    const float* __restrict__ linW, const float* __restrict__ linb,
    float* __restrict__ B2, float* __restrict__ B3,
    float* __restrict__ Z, float* __restrict__ out,
    int* __restrict__ flags)
{
    __shared__ float4 Bs4[9 * 512];     // 72 KB: B operand (+ final t arena)
    __shared__ float  redf[720];        // cross-wave reduce arena

    const int tid = threadIdx.x;
    const int bid = blockIdx.x;
    float* Bsf = reinterpret_cast<float*>(Bs4);

    // Phase 0: every block computes pre-stage into its own LDS
    pre_into_lds(tid, signal, u1, bilW, bilb, Bsf);
    __syncthreads();

    // Phase 1: LSTM 1 (+ u2 mask): LDS B -> B2
    lstm_phase<true>(bid, tid, Bs4, redf, Wih1, bih1, bhh1, u2, B2);
    grid_barrier(flags, 1);

    // Phase 2: LSTM 2: B2 -> B3
    stage_B(tid, B2, Bs4);
    __syncthreads();
    lstm_phase<false>(bid, tid, Bs4, redf, Wih2, bih2, bhh2, nullptr, B3);
    grid_barrier(flags, 2);

    // Phase 3: linear: B3 -> Z (bias folded)
    stage_B(tid, B3, Bs4);
    __syncthreads();
    linear_phase(bid, tid, Bs4, redf, linW, linb, Z);
    grid_barrier(flags, 3);

    // Phase 4: final (blocks 0..4)
    if (bid < 5) final_phase(bid, tid, Bsf, redf, Z, out);
}

// ---------------------------------------------------------------------------
extern "C" void kernel_launch(void* const* d_in, const int* in_sizes, int n_in,
                              void* d_out, int out_size, void* d_ws, size_t ws_size,
                              hipStream_t stream)
{
    const float* signal = (const float*)d_in[0];
    const float* u1     = (const float*)d_in[1];
    const float* u2     = (const float*)d_in[2];
    const float* bilW   = (const float*)d_in[3];
    const float* bilb   = (const float*)d_in[4];
    const float* Wih1   = (const float*)d_in[5];
    // d_in[6] = Whh1 : unused (h0 = 0)
    const float* bih1   = (const float*)d_in[7];
    const float* bhh1   = (const float*)d_in[8];
    const float* Wih2   = (const float*)d_in[9];
    // d_in[10] = Whh2 : unused
    const float* bih2   = (const float*)d_in[11];
    const float* bhh2   = (const float*)d_in[12];
    const float* linW   = (const float*)d_in[13];
    const float* linb   = (const float*)d_in[14];

    float* out = (float*)d_out;
    float* ws  = (float*)d_ws;

    // workspace layout (floats): B2[18432] B3[18432] Z[92160] flags[513 ints]
    float* B2    = ws;
    float* B3    = ws + 18432;
    float* Z     = ws + 36864;
    int*   flags = (int*)(ws + 36864 + 92160);

    hipMemsetAsync(flags, 0, (NBLK + 1) * sizeof(int), stream);

    k_mega<<<NBLK, 256, 0, stream>>>(signal, u1, u2, bilW, bilb,
                                     Wih1, bih1, bhh1,
                                     Wih2, bih2, bhh2,
                                     linW, linb,
                                     B2, B3, Z, out, flags);
}

// Round 10
// 86.069 us; speedup vs baseline: 4.8434x; 4.8434x over previous
//
#include <hip/hip_runtime.h>
#include <math.h>

#define IOTA_F (1.0f / 137.0f)
#define PHI_F  0.618033988749894f

__device__ __forceinline__ float sigm(float x) { return 1.0f / (1.0f + expf(-x)); }

__device__ __forceinline__ float nan2num(float v) {
    if (isnan(v)) return IOTA_F;
    if (isinf(v)) return v > 0.0f ? 1.0f : IOTA_F;
    return v;
}

// ---------------------------------------------------------------------------
// Kernel 1: instance_norm(5) -> rfft(5) -> re*im -> sigmoid -> softmax(3)
//           -> bilinear(3x3 -> 9) -> mask(u1) -> B1[9][2048]
// ---------------------------------------------------------------------------
__global__ void k_pre(const float* __restrict__ signal,  // [5][2048]
                      const float* __restrict__ u1,      // [9][2048]
                      const float* __restrict__ bilW,    // [9][3][3]
                      const float* __restrict__ bilb,    // [9]
                      float* __restrict__ B1)            // [9][2048]
{
    int s = blockIdx.x * blockDim.x + threadIdx.x;
    if (s >= 2048) return;

    float x0 = signal[0 * 2048 + s];
    float x1 = signal[1 * 2048 + s];
    float x2 = signal[2 * 2048 + s];
    float x3 = signal[3 * 2048 + s];
    float x4 = signal[4 * 2048 + s];

    float mean = (x0 + x1 + x2 + x3 + x4) * 0.2f;
    float d0 = x0 - mean, d1 = x1 - mean, d2 = x2 - mean, d3 = x3 - mean, d4 = x4 - mean;
    float var = (d0 * d0 + d1 * d1 + d2 * d2 + d3 * d3 + d4 * d4) * 0.2f;
    float r = 1.0f / sqrtf(var + 1e-9f);
    d0 *= r; d1 *= r; d2 *= r; d3 *= r; d4 *= r;

    const float c1 = 0.30901699437494742f;   // cos(2pi/5)
    const float c2 = -0.80901699437494745f;  // cos(4pi/5)
    const float s1 = 0.95105651629515357f;   // sin(2pi/5)
    const float s2 = 0.58778525229247314f;   // sin(4pi/5)

    float re1 = d0 + c1 * (d1 + d4) + c2 * (d2 + d3);
    float im1 = -(s1 * (d1 - d4) + s2 * (d2 - d3));
    float re2 = d0 + c2 * (d1 + d4) + c1 * (d2 + d3);
    float im2 = -s2 * (d1 - d4) + s1 * (d2 - d3);

    float p1 = nan2num(re1 * im1);
    float p2 = nan2num(re2 * im2);
    float g0 = 0.5f;                 // k=0: imag == 0 -> sigmoid(0) = 0.5
    float g1 = sigm(p1);
    float g2 = sigm(p2);

    float mx = fmaxf(g0, fmaxf(g1, g2));
    float e0 = expf(g0 - mx), e1 = expf(g1 - mx), e2 = expf(g2 - mx);
    float inv = 1.0f / (e0 + e1 + e2);
    float w[3] = { e0 * inv, e1 * inv, e2 * inv };

    #pragma unroll
    for (int kk = 0; kk < 9; ++kk) {
        float acc = bilb[kk];
        #pragma unroll
        for (int i = 0; i < 3; ++i)
            #pragma unroll
            for (int j = 0; j < 3; ++j)
                acc += w[i] * bilW[kk * 9 + i * 3 + j] * w[j];
        float mask = (u1[kk * 2048 + s] < PHI_F) ? 1.0f : 0.0f;
        B1[kk * 2048 + s] = IOTA_F + acc * mask;
    }
}

// ---------------------------------------------------------------------------
// Kernel 2: fused LSTM layer (gemv + nonlinearity) — round-4 inner loop,
// occupancy doubled: block = 512 threads = 8 waves (8-way K-split of 256
// floats each). Grid 512 = 2 blocks/CU = 16 waves/CU.
//   group g (16 lanes) of each wave owns q = blockIdx*4+g and its 3 live
//   gate rows {q, 4096+q, 6144+q} (f dead: c0 = 0).
//   shfl reduce -> LDS[8][4][3][9] -> epilogue (36 threads) sums 8 waves,
//   adds biases, h = sig(o)*tanh(sig(i)*tanh(g)) (+mask), writes Bout.
// ---------------------------------------------------------------------------
template <bool MASK>
__global__ __launch_bounds__(512, 4) void k_lstm_fused(
    const float* __restrict__ Bv,   // [9][2048]
    const float* __restrict__ W,    // [8192][2048]
    const float* __restrict__ b1,   // [8192]
    const float* __restrict__ b2,   // [8192]
    const float* __restrict__ u,    // [9][2048] or null
    float* __restrict__ Bout)       // [9][2048]
{
    __shared__ float lds[8][4][3][9];

    const int tid  = threadIdx.x;
    const int w    = tid >> 6;      // wave 0..7 = K-chunk
    const int lane = tid & 63;
    const int grp  = lane >> 4;     // q within block
    const int li   = lane & 15;

    const int q = blockIdx.x * 4 + grp;

    const float4* __restrict__ B4 = reinterpret_cast<const float4*>(Bv);
    const float4* __restrict__ Wi = reinterpret_cast<const float4*>(W) + (size_t)q * 512;
    const float4* __restrict__ Wg = Wi + (size_t)4096 * 512;
    const float4* __restrict__ Wo = Wi + (size_t)6144 * 512;

    float acc[3][9];
    #pragma unroll
    for (int r = 0; r < 3; ++r)
        #pragma unroll
        for (int m = 0; m < 9; ++m) acc[r][m] = 0.0f;

    const int kb4 = w * 64;         // float4 base of this wave's K chunk

    #pragma unroll 2
    for (int it = 0; it < 4; ++it) {
        const int idx = kb4 + it * 16 + li;
        float4 bv[9];
        #pragma unroll
        for (int m = 0; m < 9; ++m) bv[m] = B4[m * 512 + idx];
        float4 wv0 = Wi[idx];
        float4 wv1 = Wg[idx];
        float4 wv2 = Wo[idx];
        #pragma unroll
        for (int m = 0; m < 9; ++m) {
            acc[0][m] = fmaf(wv0.x, bv[m].x, acc[0][m]);
            acc[0][m] = fmaf(wv0.y, bv[m].y, acc[0][m]);
            acc[0][m] = fmaf(wv0.z, bv[m].z, acc[0][m]);
            acc[0][m] = fmaf(wv0.w, bv[m].w, acc[0][m]);
            acc[1][m] = fmaf(wv1.x, bv[m].x, acc[1][m]);
            acc[1][m] = fmaf(wv1.y, bv[m].y, acc[1][m]);
            acc[1][m] = fmaf(wv1.z, bv[m].z, acc[1][m]);
            acc[1][m] = fmaf(wv1.w, bv[m].w, acc[1][m]);
            acc[2][m] = fmaf(wv2.x, bv[m].x, acc[2][m]);
            acc[2][m] = fmaf(wv2.y, bv[m].y, acc[2][m]);
            acc[2][m] = fmaf(wv2.z, bv[m].z, acc[2][m]);
            acc[2][m] = fmaf(wv2.w, bv[m].w, acc[2][m]);
        }
    }

    #pragma unroll
    for (int r = 0; r < 3; ++r)
        #pragma unroll
        for (int m = 0; m < 9; ++m) {
            float v = acc[r][m];
            v += __shfl_xor(v, 1);
            v += __shfl_xor(v, 2);
            v += __shfl_xor(v, 4);
            v += __shfl_xor(v, 8);
            acc[r][m] = v;
        }

    if (li == 0) {
        #pragma unroll
        for (int r = 0; r < 3; ++r)
            #pragma unroll
            for (int m = 0; m < 9; ++m)
                lds[w][grp][r][m] = acc[r][m];
    }
    __syncthreads();

    if (tid < 36) {
        const int qq = tid / 9;
        const int m  = tid - qq * 9;
        const int qg = blockIdx.x * 4 + qq;
        float iv = 0.0f, gv = 0.0f, ov = 0.0f;
        #pragma unroll
        for (int ww = 0; ww < 8; ++ww) {
            iv += lds[ww][qq][0][m];
            gv += lds[ww][qq][1][m];
            ov += lds[ww][qq][2][m];
        }
        iv += b1[qg] + b2[qg];
        gv += b1[4096 + qg] + b2[4096 + qg];
        ov += b1[6144 + qg] + b2[6144 + qg];
        float c = sigm(iv) * tanhf(gv);
        float h = sigm(ov) * tanhf(c);
        if (MASK) h = IOTA_F + h * ((u[m * 2048 + qg] < PHI_F) ? 1.0f : 0.0f);
        Bout[m * 2048 + qg] = h;
    }
}

// ---------------------------------------------------------------------------
// Kernel 3: linear gemv — round-4 inner loop, 8-wave block (8-way K-split).
// Block covers 20 rows (grid 512 = 2 blocks/CU); group g owns rows
// rowB+g*5 .. +4. LDS[8][20][9] cross-wave reduce; bias added; writes Z.
// ---------------------------------------------------------------------------
template <int R>
__global__ __launch_bounds__(512, 4) void k_gemvR(
    const float* __restrict__ Bv,    // [9][2048]
    const float* __restrict__ W,     // [nrows][2048]
    const float* __restrict__ bias,  // [nrows]
    float* __restrict__ Out,         // [9][nrows]
    int nrows)
{
    __shared__ float lds[8][4 * R][9];

    const int tid  = threadIdx.x;
    const int w    = tid >> 6;
    const int lane = tid & 63;
    const int grp  = lane >> 4;
    const int li   = lane & 15;

    const int rowB = blockIdx.x * 4 * R;           // block's first row
    const int row0 = rowB + grp * R;               // group's first row

    const float4* __restrict__ B4 = reinterpret_cast<const float4*>(Bv);
    const float4* __restrict__ W0 = reinterpret_cast<const float4*>(W) + (size_t)row0 * 512;

    float acc[R][9];
    #pragma unroll
    for (int r = 0; r < R; ++r)
        #pragma unroll
        for (int m = 0; m < 9; ++m) acc[r][m] = 0.0f;

    const int kb4 = w * 64;

    #pragma unroll 2
    for (int it = 0; it < 4; ++it) {
        const int idx = kb4 + it * 16 + li;
        float4 bv[9];
        #pragma unroll
        for (int m = 0; m < 9; ++m) bv[m] = B4[m * 512 + idx];
        #pragma unroll
        for (int r = 0; r < R; ++r) {
            float4 wv = W0[(size_t)r * 512 + idx];
            #pragma unroll
            for (int m = 0; m < 9; ++m) {
                acc[r][m] = fmaf(wv.x, bv[m].x, acc[r][m]);
                acc[r][m] = fmaf(wv.y, bv[m].y, acc[r][m]);
                acc[r][m] = fmaf(wv.z, bv[m].z, acc[r][m]);
                acc[r][m] = fmaf(wv.w, bv[m].w, acc[r][m]);
            }
        }
    }

    #pragma unroll
    for (int r = 0; r < R; ++r)
        #pragma unroll
        for (int m = 0; m < 9; ++m) {
            float v = acc[r][m];
            v += __shfl_xor(v, 1);
            v += __shfl_xor(v, 2);
            v += __shfl_xor(v, 4);
            v += __shfl_xor(v, 8);
            acc[r][m] = v;
        }

    if (li == 0) {
        #pragma unroll
        for (int r = 0; r < R; ++r)
            #pragma unroll
            for (int m = 0; m < 9; ++m)
                lds[w][grp * R + r][m] = acc[r][m];
    }
    __syncthreads();

    for (int t = tid; t < 4 * R * 9; t += 512) {
        const int row = t / 9;
        const int m   = t - row * 9;
        float v = 0.0f;
        #pragma unroll
        for (int ww = 0; ww < 8; ++ww) v += lds[ww][row][m];
        const int grow = rowB + row;
        Out[(size_t)m * nrows + grow] = v + bias[grow];
    }
}

// ---------------------------------------------------------------------------
// Kernel 4: per sample a: t[s] = sum_{k=0..8} Z[a*18432 + s*9 + k];
//           instance_norm over s; softmax over s.  (Z includes lin bias.)
// ---------------------------------------------------------------------------
__device__ __forceinline__ float block_reduce(float v, float* red, int tid, int op) {
    #pragma unroll
    for (int off = 32; off > 0; off >>= 1) {
        float o = __shfl_xor(v, off);
        v = op ? fmaxf(v, o) : (v + o);
    }
    __syncthreads();
    if ((tid & 63) == 0) red[tid >> 6] = v;
    __syncthreads();
    float r = red[0];
    #pragma unroll
    for (int w = 1; w < 8; ++w) r = op ? fmaxf(r, red[w]) : (r + red[w]);
    return r;
}

__global__ void k_final(const float* __restrict__ Z,  // [92160] flat
                        float* __restrict__ out)      // [5][2048]
{
    __shared__ float t[2048];
    __shared__ float red[8];
    const int a = blockIdx.x;
    const int tid = threadIdx.x;  // 512 threads

    for (int s = tid; s < 2048; s += 512) {
        const float* zp = Z + a * 18432 + s * 9;
        float acc = 0.0f;
        #pragma unroll
        for (int k = 0; k < 9; ++k) acc += zp[k];
        t[s] = acc;
    }
    __syncthreads();

    float l0 = t[tid], l1 = t[tid + 512], l2 = t[tid + 1024], l3 = t[tid + 1536];

    float ssum = block_reduce(l0 + l1 + l2 + l3, red, tid, 0);
    float mean = ssum * (1.0f / 2048.0f);
    float e0 = l0 - mean, e1 = l1 - mean, e2 = l2 - mean, e3 = l3 - mean;
    float vsum = block_reduce(e0 * e0 + e1 * e1 + e2 * e2 + e3 * e3, red, tid, 0);
    float rstd = 1.0f / sqrtf(vsum * (1.0f / 2048.0f) + 1e-9f);
    float xn0 = e0 * rstd, xn1 = e1 * rstd, xn2 = e2 * rstd, xn3 = e3 * rstd;

    float mx = block_reduce(fmaxf(fmaxf(xn0, xn1), fmaxf(xn2, xn3)), red, tid, 1);
    float ex0 = expf(xn0 - mx), ex1 = expf(xn1 - mx), ex2 = expf(xn2 - mx), ex3 = expf(xn3 - mx);
    float esum = block_reduce(ex0 + ex1 + ex2 + ex3, red, tid, 0);
    float inv = 1.0f / esum;

    out[a * 2048 + tid]        = ex0 * inv;
    out[a * 2048 + tid + 512]  = ex1 * inv;
    out[a * 2048 + tid + 1024] = ex2 * inv;
    out[a * 2048 + tid + 1536] = ex3 * inv;
}

// ---------------------------------------------------------------------------
extern "C" void kernel_launch(void* const* d_in, const int* in_sizes, int n_in,
                              void* d_out, int out_size, void* d_ws, size_t ws_size,
                              hipStream_t stream)
{
    const float* signal = (const float*)d_in[0];
    const float* u1     = (const float*)d_in[1];
    const float* u2     = (const float*)d_in[2];
    const float* bilW   = (const float*)d_in[3];
    const float* bilb   = (const float*)d_in[4];
    const float* Wih1   = (const float*)d_in[5];
    // d_in[6] = Whh1 : unused (h0 = 0)
    const float* bih1   = (const float*)d_in[7];
    const float* bhh1   = (const float*)d_in[8];
    const float* Wih2   = (const float*)d_in[9];
    // d_in[10] = Whh2 : unused
    const float* bih2   = (const float*)d_in[11];
    const float* bhh2   = (const float*)d_in[12];
    const float* linW   = (const float*)d_in[13];
    const float* linb   = (const float*)d_in[14];

    float* out = (float*)d_out;
    float* ws  = (float*)d_ws;

    // workspace layout (floats): B1[18432] B2[18432] Z[92160]  (~516 KB)
    float* B1 = ws;
    float* B2 = ws + 18432;
    float* B3 = B1;             // reuse (B1 dead after LSTM 1)
    float* Z  = ws + 36864;

    k_pre<<<8, 256, 0, stream>>>(signal, u1, bilW, bilb, B1);

    // LSTM layers: 512 blocks x 512 threads = 2 blocks/CU, 16 waves/CU
    k_lstm_fused<true><<<512, 512, 0, stream>>>(B1, Wih1, bih1, bhh1, u2, B2);
    k_lstm_fused<false><<<512, 512, 0, stream>>>(B2, Wih2, bih2, bhh2, nullptr, B3);

    // Linear: 10240 rows, 20 rows/block -> 512 blocks
    k_gemvR<5><<<512, 512, 0, stream>>>(B3, linW, linb, Z, 10240);

    // reshape-sum over 9, instance norm + softmax over 2048
    k_final<<<5, 512, 0, stream>>>(Z, out);
}